// Round 1
// baseline (461.690 us; speedup 1.0000x reference)
//
#include <hip/hip_runtime.h>

typedef __attribute__((ext_vector_type(8))) short short8;
typedef __attribute__((ext_vector_type(4))) float f32x4;
typedef __attribute__((ext_vector_type(4))) unsigned short us4;

#define MFMA16(a,b,c) __builtin_amdgcn_mfma_f32_16x16x32_bf16(a,b,c,0,0,0)

#define EMBED 768
#define HEADS 12
#define DK 64
#define M_MISS 2048
#define N_EX 6144
#define NSEC 8192

__device__ __forceinline__ unsigned short f2bf(float f){
  unsigned u = __builtin_bit_cast(unsigned, f);
  u += 0x7FFFu + ((u >> 16) & 1u);
  return (unsigned short)(u >> 16);
}

// ---------------- transpose + cast weights: Wt[which][c][e] = W[e][c] ----------------
__global__ __launch_bounds__(256) void k_transpose_w(
    const float* __restrict__ Wq, const float* __restrict__ Wk,
    const float* __restrict__ Wv, unsigned short* __restrict__ Wt)
{
  int bid = blockIdx.x;
  int which = bid / 144, t = bid % 144;
  int er0 = (t / 12) * 64, cc0 = (t % 12) * 64;
  const float* W = (which == 0) ? Wq : ((which == 1) ? Wk : Wv);
  unsigned short* dst = Wt + (long)which * EMBED * EMBED;
  __shared__ float tile[64][65];
  int tid = threadIdx.x;
  {
    int e = tid >> 4, c4 = (tid & 15) * 4;
    for (int i = 0; i < 4; i++) {
      float4 v = *reinterpret_cast<const float4*>(&W[(long)(er0 + e + i*16) * EMBED + cc0 + c4]);
      tile[e + i*16][c4 + 0] = v.x; tile[e + i*16][c4 + 1] = v.y;
      tile[e + i*16][c4 + 2] = v.z; tile[e + i*16][c4 + 3] = v.w;
    }
  }
  __syncthreads();
  {
    int c = tid >> 4, e4 = (tid & 15) * 4;
    for (int i = 0; i < 4; i++) {
      us4 u;
      for (int j = 0; j < 4; j++) u[j] = f2bf(tile[e4 + j][c + i*16]);
      *reinterpret_cast<us4*>(&dst[(long)(cc0 + c + i*16) * EMBED + er0 + e4]) = u;
    }
  }
}

// ---------------- copy ehr -> out (full table passthrough) ----------------
__global__ __launch_bounds__(256) void k_copy(const float4* __restrict__ s, float4* __restrict__ d, int n){
  int g = blockIdx.x * 256 + threadIdx.x;
  if (g < n) d[g] = s[g];
}

// ---------------- gather cooc_bias into tail 64 dims of Qp/Kp ----------------
__global__ __launch_bounds__(256) void k_pack_cooc(
    const float* __restrict__ cooc, const int* __restrict__ idx, int count,
    unsigned short* __restrict__ dst)
{
  int g = blockIdx.x * 256 + threadIdx.x;
  int total = HEADS * count * 16;
  if (g >= total) return;
  int d4 = (g & 15) * 4;
  int r  = (g >> 4) % count;
  int h  = (g >> 4) / count;
  int src_row = idx[r];
  float4 v = *reinterpret_cast<const float4*>(&cooc[((long)h * NSEC + src_row) * DK + d4]);
  us4 o; o[0] = f2bf(v.x); o[1] = f2bf(v.y); o[2] = f2bf(v.z); o[3] = f2bf(v.w);
  *reinterpret_cast<us4*>(&dst[((long)h * count + r) * 128 + 64 + d4]) = o;
}

// ---------------- gather-GEMM: gather(ehr,idx) @ W + b, packed per mode ----------------
// mode 0: Qp[h][m][d] = val*0.125 (bf16)   rows stride 2048, inner 128
// mode 1: Kp[h][n][d] = val                 rows stride 6144, inner 128
// mode 2: Vt[h][d][n] = val                 transposed for PV B-frags
__global__ __launch_bounds__(256) void k_gemm_qkv(
    const float* __restrict__ ehr, const int* __restrict__ idx, int nrb,
    const unsigned short* __restrict__ Wt, const float* __restrict__ bias,
    unsigned short* __restrict__ dst, int mode)
{
  __shared__ unsigned char sA[128 * 64];   // 128 rows x 32 bf16 (64B rows), swizzled
  __shared__ unsigned char sB[128 * 64];
  int tid = threadIdx.x;
  int rb = blockIdx.x % nrb, cb = blockIdx.x / nrb;
  int row0 = rb * 128, col0 = cb * 128;
  int wv = tid >> 6, lane = tid & 63, l15 = lane & 15, lg = lane >> 4;
  int wm = wv >> 1, wn = wv & 1;

  int ar = tid >> 2, as = tid & 3;
  long g0 = idx[row0 + ar];
  long g1 = idx[row0 + ar + 64];
  const float* ap0 = ehr + g0 * EMBED + as * 8;
  const float* ap1 = ehr + g1 * EMBED + as * 8;
  const unsigned short* bp0 = Wt + (long)(col0 + ar) * EMBED + as * 8;
  const unsigned short* bp1 = Wt + (long)(col0 + ar + 64) * EMBED + as * 8;
  unsigned aoff = (unsigned)ar * 64 + ((unsigned)(as ^ (ar & 3)) << 4);  // (ar+64)&3 == ar&3

  f32x4 acc[4][4];
  for (int i = 0; i < 4; i++) for (int j = 0; j < 4; j++) acc[i][j] = (f32x4){0.f,0.f,0.f,0.f};

  for (int k0 = 0; k0 < EMBED; k0 += 32) {
    __syncthreads();
    {
      float4 u0 = *reinterpret_cast<const float4*>(ap0 + k0);
      float4 u1 = *reinterpret_cast<const float4*>(ap0 + k0 + 4);
      short8 p;
      p[0]=(short)f2bf(u0.x); p[1]=(short)f2bf(u0.y); p[2]=(short)f2bf(u0.z); p[3]=(short)f2bf(u0.w);
      p[4]=(short)f2bf(u1.x); p[5]=(short)f2bf(u1.y); p[6]=(short)f2bf(u1.z); p[7]=(short)f2bf(u1.w);
      *reinterpret_cast<short8*>(&sA[aoff]) = p;
      u0 = *reinterpret_cast<const float4*>(ap1 + k0);
      u1 = *reinterpret_cast<const float4*>(ap1 + k0 + 4);
      p[0]=(short)f2bf(u0.x); p[1]=(short)f2bf(u0.y); p[2]=(short)f2bf(u0.z); p[3]=(short)f2bf(u0.w);
      p[4]=(short)f2bf(u1.x); p[5]=(short)f2bf(u1.y); p[6]=(short)f2bf(u1.z); p[7]=(short)f2bf(u1.w);
      *reinterpret_cast<short8*>(&sA[aoff + 64 * 64]) = p;
      *reinterpret_cast<short8*>(&sB[aoff]) = *reinterpret_cast<const short8*>(bp0 + k0);
      *reinterpret_cast<short8*>(&sB[aoff + 64 * 64]) = *reinterpret_cast<const short8*>(bp1 + k0);
    }
    __syncthreads();
    short8 a[4], b[4];
    for (int i = 0; i < 4; i++) {
      unsigned r = (unsigned)(wm * 64 + 16 * i + l15);
      a[i] = *reinterpret_cast<const short8*>(&sA[r * 64 + (((unsigned)lg ^ (r & 3)) << 4)]);
      unsigned c = (unsigned)(wn * 64 + 16 * i + l15);
      b[i] = *reinterpret_cast<const short8*>(&sB[c * 64 + (((unsigned)lg ^ (c & 3)) << 4)]);
    }
    for (int i = 0; i < 4; i++)
      for (int j = 0; j < 4; j++)
        acc[i][j] = MFMA16(a[i], b[j], acc[i][j]);
  }

  for (int i = 0; i < 4; i++) {
    int mrow = row0 + wm * 64 + 16 * i + lg * 4;
    for (int j = 0; j < 4; j++) {
      int cg = col0 + wn * 64 + 16 * j + l15;
      float bv = bias[cg];
      int h = cg >> 6, d = cg & 63;
      if (mode == 2) {
        us4 u;
        for (int r = 0; r < 4; r++) u[r] = f2bf(acc[i][j][r] + bv);
        *reinterpret_cast<us4*>(&dst[((long)h * 64 + d) * N_EX + mrow]) = u;
      } else if (mode == 0) {
        for (int r = 0; r < 4; r++)
          dst[((long)h * M_MISS + mrow + r) * 128 + d] = f2bf((acc[i][j][r] + bv) * 0.125f);
      } else {
        for (int r = 0; r < 4; r++)
          dst[((long)h * N_EX + mrow + r) * 128 + d] = f2bf(acc[i][j][r] + bv);
      }
    }
  }
}

// ---------------- flash attention: D_qk=128, D_v=64, online softmax ----------------
// grid 384 = 12 heads x 32 q-blocks(64 rows). 2 waves x 32 rows. KVBLK=64.
__global__ __launch_bounds__(128) void k_attn(
    const unsigned short* __restrict__ Qp, const unsigned short* __restrict__ Kp,
    const unsigned short* __restrict__ Vt, const int* __restrict__ missing,
    float* __restrict__ out)
{
  // XCD-chunked swizzle: 384 = 8 XCDs x 48, keeps each head's K/V in one XCD L2
  int wg = (blockIdx.x & 7) * 48 + (blockIdx.x >> 3);
  int h = wg / 32, qb = wg % 32;
  int tid = threadIdx.x;
  int wv = tid >> 6, lane = tid & 63, l15 = lane & 15, lg = lane >> 4;

  __shared__ unsigned char sK[64 * 256];      // 64 n-rows x 128 bf16, swizzled (slot ^ row&7)
  __shared__ unsigned char sV[64 * 128];      // 64 dv-rows x 64 bf16, swizzled
  __shared__ unsigned char sP[2][32 * 128];   // per-wave P: 32 m-rows x 64 bf16

  int q0 = qb * 64;
  short8 qf[2][4];
  for (int ms = 0; ms < 2; ms++) {
    int m = q0 + wv * 32 + ms * 16 + l15;
    const unsigned short* qrow = Qp + ((long)h * M_MISS + m) * 128 + lg * 8;
    for (int t = 0; t < 4; t++)
      qf[ms][t] = *reinterpret_cast<const short8*>(qrow + t * 32);
  }

  f32x4 oacc[2][4];
  float m_run[2][4], l_run[2][4];
  for (int ms = 0; ms < 2; ms++)
    for (int r = 0; r < 4; r++) { m_run[ms][r] = -3.0e38f; l_run[ms][r] = 0.f; }
  for (int ms = 0; ms < 2; ms++)
    for (int ds = 0; ds < 4; ds++) oacc[ms][ds] = (f32x4){0.f,0.f,0.f,0.f};

  int srow = tid >> 1, shalf = tid & 1;

  for (int n0 = 0; n0 < N_EX; n0 += 64) {
    __syncthreads();
    {
      const unsigned short* src = Kp + ((long)h * N_EX + n0 + srow) * 128 + shalf * 64;
      for (int i = 0; i < 8; i++) {
        short8 v = *reinterpret_cast<const short8*>(src + i * 8);
        unsigned slot = (unsigned)(shalf * 8 + i);
        *reinterpret_cast<short8*>(&sK[(unsigned)srow * 256 + ((slot ^ ((unsigned)srow & 7)) << 4)]) = v;
      }
      const unsigned short* vsrc = Vt + ((long)h * 64 + srow) * N_EX + n0 + shalf * 32;
      for (int i = 0; i < 4; i++) {
        short8 v = *reinterpret_cast<const short8*>(vsrc + i * 8);
        unsigned slot = (unsigned)(shalf * 4 + i);
        *reinterpret_cast<short8*>(&sV[(unsigned)srow * 128 + ((slot ^ ((unsigned)srow & 7)) << 4)]) = v;
      }
    }
    __syncthreads();

    // S = Q'K'^T (per wave: 32 m x 64 n)
    f32x4 s_acc[2][4];
    for (int ms = 0; ms < 2; ms++) for (int ns = 0; ns < 4; ns++) s_acc[ms][ns] = (f32x4){0.f,0.f,0.f,0.f};
    for (int t = 0; t < 4; t++) {
      for (int ns = 0; ns < 4; ns++) {
        unsigned krow = (unsigned)(ns * 16 + l15);
        unsigned slot = ((unsigned)(t * 4 + lg)) ^ (krow & 7);
        short8 kf = *reinterpret_cast<const short8*>(&sK[krow * 256 + (slot << 4)]);
        s_acc[0][ns] = MFMA16(qf[0][t], kf, s_acc[0][ns]);
        s_acc[1][ns] = MFMA16(qf[1][t], kf, s_acc[1][ns]);
      }
    }

    // online softmax + P -> LDS (per-wave region, no barrier needed)
    for (int ms = 0; ms < 2; ms++) {
      for (int r = 0; r < 4; r++) {
        float mx = fmaxf(fmaxf(s_acc[ms][0][r], s_acc[ms][1][r]),
                         fmaxf(s_acc[ms][2][r], s_acc[ms][3][r]));
        mx = fmaxf(mx, __shfl_xor(mx, 1));
        mx = fmaxf(mx, __shfl_xor(mx, 2));
        mx = fmaxf(mx, __shfl_xor(mx, 4));
        mx = fmaxf(mx, __shfl_xor(mx, 8));
        float mn = fmaxf(m_run[ms][r], mx);
        float sc = __expf(m_run[ms][r] - mn);
        m_run[ms][r] = mn;
        unsigned row = (unsigned)(ms * 16 + lg * 4 + r);
        float lsum = 0.f;
        for (int ns = 0; ns < 4; ns++) {
          float p = __expf(s_acc[ms][ns][r] - mn);
          lsum += p;
          unsigned col = (unsigned)(l15 + 16 * ns);
          unsigned slot = (col >> 3) ^ (row & 7);
          *reinterpret_cast<unsigned short*>(&sP[wv][row * 128 + (slot << 4) + ((col & 7) * 2)]) = f2bf(p);
        }
        lsum += __shfl_xor(lsum, 1);
        lsum += __shfl_xor(lsum, 2);
        lsum += __shfl_xor(lsum, 4);
        lsum += __shfl_xor(lsum, 8);
        l_run[ms][r] = l_run[ms][r] * sc + lsum;
        for (int ds = 0; ds < 4; ds++) {
          oacc[ms][ds][r] *= sc;
        }
      }
    }

    // O += P V  (A-frag from sP, B-frag from sV)
    for (int t2 = 0; t2 < 2; t2++) {
      short8 pa[2];
      for (int ms = 0; ms < 2; ms++) {
        unsigned row = (unsigned)(ms * 16 + l15);
        unsigned slot = ((unsigned)(t2 * 4 + lg)) ^ (row & 7);
        pa[ms] = *reinterpret_cast<const short8*>(&sP[wv][row * 128 + (slot << 4)]);
      }
      for (int ds = 0; ds < 4; ds++) {
        unsigned vrow = (unsigned)(ds * 16 + l15);
        unsigned slot = ((unsigned)(t2 * 4 + lg)) ^ (vrow & 7);
        short8 vf = *reinterpret_cast<const short8*>(&sV[vrow * 128 + (slot << 4)]);
        oacc[0][ds] = MFMA16(pa[0], vf, oacc[0][ds]);
        oacc[1][ds] = MFMA16(pa[1], vf, oacc[1][ds]);
      }
    }
  }

  for (int ms = 0; ms < 2; ms++) {
    int mbase = q0 + wv * 32 + ms * 16 + lg * 4;
    for (int r = 0; r < 4; r++) {
      int orow = missing[mbase + r];
      float inv = 1.0f / l_run[ms][r];
      for (int ds = 0; ds < 4; ds++) {
        int dv = l15 + 16 * ds;
        out[(long)orow * EMBED + h * 64 + dv] = oacc[ms][ds][r] * inv;
      }
    }
  }
}

extern "C" void kernel_launch(void* const* d_in, const int* in_sizes, int n_in,
                              void* d_out, int out_size, void* d_ws, size_t ws_size,
                              hipStream_t stream) {
  const float* ehr     = (const float*)d_in[0];
  const int*   exist   = (const int*)  d_in[1];
  const int*   missing = (const int*)  d_in[2];
  const float* Wq = (const float*)d_in[3];
  const float* bq = (const float*)d_in[4];
  const float* Wk = (const float*)d_in[5];
  const float* bk = (const float*)d_in[6];
  const float* Wv = (const float*)d_in[7];
  const float* bv = (const float*)d_in[8];
  const float* cooc = (const float*)d_in[9];
  float* out = (float*)d_out;

  char* ws = (char*)d_ws;
  unsigned short* Wt = (unsigned short*)(ws);                      // 3*768*768*2  = 3538944
  unsigned short* Qp = (unsigned short*)(ws + 3538944);            // 12*2048*128*2 = 6291456
  unsigned short* Kp = (unsigned short*)(ws + 9830400);            // 12*6144*128*2 = 18874368
  unsigned short* Vt = (unsigned short*)(ws + 28704768);           // 12*64*6144*2  = 9437184

  k_transpose_w<<<432, 256, 0, stream>>>(Wq, Wk, Wv, Wt);
  k_copy<<<(NSEC * EMBED / 4 + 255) / 256, 256, 0, stream>>>(
      (const float4*)ehr, (float4*)out, NSEC * EMBED / 4);
  k_pack_cooc<<<(HEADS * M_MISS * 16 + 255) / 256, 256, 0, stream>>>(cooc, missing, M_MISS, Qp);
  k_pack_cooc<<<(HEADS * N_EX * 16 + 255) / 256, 256, 0, stream>>>(cooc, exist, N_EX, Kp);
  k_gemm_qkv<<<(M_MISS / 128) * 6, 256, 0, stream>>>(ehr, missing, M_MISS / 128, Wt,             bq, Qp, 0);
  k_gemm_qkv<<<(N_EX  / 128) * 6, 256, 0, stream>>>(ehr, exist,   N_EX  / 128, Wt + 768 * 768,   bk, Kp, 1);
  k_gemm_qkv<<<(N_EX  / 128) * 6, 256, 0, stream>>>(ehr, exist,   N_EX  / 128, Wt + 2 * 768 * 768, bv, Vt, 2);
  k_attn<<<384, 128, 0, stream>>>(Qp, Kp, Vt, missing, out);
}